// Round 5
// baseline (3706.679 us; speedup 1.0000x reference)
//
#include <hip/hip_runtime.h>
#include <hip/hip_bf16.h>
#include <hip/hip_fp16.h>
#include <math.h>

// Problem constants
#define HH 320
#define WW 320
#define NP (HH*WW)        // 102400
#define CC 32
#define DD 32
#define H2 160
#define W2 160
#define N2 (H2*W2)
#define H4 80
#define W4 80
#define N4 (H4*W4)
#define H8 40
#define W8 40
#define N8 (H8*W8)

// stage A / U tile: 16 wide x 8 high
#define AHW 18
#define AHH 10
#define ANH (AHW*AHH)      // 180
#define ABUF_STRIDE 184    // buf row stride (per-channel), breaks pow2 banks

// stage U LDS layouts (padded strides to avoid bank conflicts)
#define U3_PX 24           // 6x4 quarter-res region
#define U3_STRIDE 33
#define U2_PX 60           // 10x6 half-res region
#define U2_STRIDE 17
#define U1_PX 180          // 18x10 full-res halo
#define U1_STRIDE 9

#define SMEM_FLOATS (U3_PX*U3_STRIDE + U2_PX*U2_STRIDE + U1_PX*U1_STRIDE)  // 3432 fl = 13728 B
// stage A uses 8*ABUF_STRIDE = 1472 floats (prefix)

// ring strides (floats); all rings NHWC: [pix][ch]
#define C1SZ (8*NP)
#define C2SZ (16*N2)
#define C3SZ (32*N4)
#define C4SZ (64*N8)

// workspace layout (float offsets)
#define OFF_REL  0
#define OFF_FH   64
#define FH_FLOATS (3*NP*32/2)              // fp16 NHWC feats: 4,915,200 floats
#define OFF_C1R  (OFF_FH + FH_FLOATS)      // ring of 5
#define OFF_C2R  (OFF_C1R + 5*C1SZ)        // ring of 4
#define OFF_C3R  (OFF_C2R + 4*C2SZ)        // ring of 3
#define OFF_C4R  (OFF_C3R + 3*C3SZ)        // ring of 2
#define OFF_ESUM (OFF_C4R + 2*C4SZ)
#define OFF_DIMG (OFF_ESUM + NP)
#define OFF_MAXP (OFF_DIMG + NP)
#define OFF_END  (OFF_MAXP + NP)           // ~47 MB

// uber grid: block ranges
#define A_END 800
#define B_END 1600
#define C_END 2000
#define D_END 2208
#define TOT_BLK 3008

// ---------------- helpers ----------------
__device__ __forceinline__ void load8h(const __half* b, float o[8]) {
    float4 f = *reinterpret_cast<const float4*>(b);
    const __half2* h = reinterpret_cast<const __half2*>(&f);
#pragma unroll
    for (int j = 0; j < 4; j++) { float2 t = __half22float2(h[j]); o[2*j] = t.x; o[2*j+1] = t.y; }
}
__device__ __forceinline__ void load8f(const float* b, float o[8]) {
    float4 x = reinterpret_cast<const float4*>(b)[0];
    float4 y = reinterpret_cast<const float4*>(b)[1];
    o[0]=x.x; o[1]=x.y; o[2]=x.z; o[3]=x.w; o[4]=y.x; o[5]=y.y; o[6]=y.z; o[7]=y.w;
}
__device__ __forceinline__ void load16f(const float* b, float o[16]) { load8f(b,o); load8f(b+8,o+8); }

// ---------------- prep: rel = proj[v] @ inv(proj[0]), v=1,2 ----------------
__global__ void k_prep(const float* __restrict__ proj, float* __restrict__ rel) {
    if (threadIdx.x != 0 || blockIdx.x != 0) return;
    double a[4][8];
    for (int i = 0; i < 4; i++)
        for (int j = 0; j < 4; j++) {
            a[i][j] = (double)proj[i*4 + j];
            a[i][j+4] = (i == j) ? 1.0 : 0.0;
        }
    for (int c = 0; c < 4; c++) {
        int pv = c; double best = fabs(a[c][c]);
        for (int r = c+1; r < 4; r++) {
            double v = fabs(a[r][c]);
            if (v > best) { best = v; pv = r; }
        }
        if (pv != c)
            for (int j = 0; j < 8; j++) { double t = a[c][j]; a[c][j] = a[pv][j]; a[pv][j] = t; }
        double inv = 1.0 / a[c][c];
        for (int j = 0; j < 8; j++) a[c][j] *= inv;
        for (int r = 0; r < 4; r++) if (r != c) {
            double f = a[r][c];
            for (int j = 0; j < 8; j++) a[r][j] -= f * a[c][j];
        }
    }
    for (int v = 1; v < 3; v++) {
        const float* P = proj + v*16;
        double rm[4][4];
        for (int i = 0; i < 4; i++)
            for (int j = 0; j < 4; j++) {
                double s = 0.0;
                for (int k = 0; k < 4; k++) s += (double)P[i*4 + k] * a[k][j+4];
                rm[i][j] = s;
            }
        float* o = rel + (v-1)*12;
        o[0]=(float)rm[0][0]; o[1]=(float)rm[0][1]; o[2]=(float)rm[0][2];
        o[3]=(float)rm[1][0]; o[4]=(float)rm[1][1]; o[5]=(float)rm[1][2];
        o[6]=(float)rm[2][0]; o[7]=(float)rm[2][1]; o[8]=(float)rm[2][2];
        o[9]=(float)rm[0][3]; o[10]=(float)rm[1][3]; o[11]=(float)rm[2][3];
    }
}

// ---------------- one-time: feats NCHW fp32 -> NHWC fp16 ----------------
__global__ __launch_bounds__(256) void k_tofp16(const float* __restrict__ feats,
                                                __half* __restrict__ fh) {
    int i = blockIdx.x*256 + threadIdx.x;     // over 3*NP pixels (view-major)
    if (i >= 3*NP) return;
    int v = i / NP, p = i - v*NP;
    const float* src = feats + (size_t)v*CC*NP + p;
    union { __half h[32]; float4 f4[4]; } u;
#pragma unroll
    for (int c = 0; c < 32; c++) u.h[c] = __float2half(src[(size_t)c*NP]);
    float4* dst = (float4*)(fh + (size_t)i*32);
#pragma unroll
    for (int q = 0; q < 4; q++) dst[q] = u.f4[q];
}

// ================= stage device functions (128 threads each) =================

// A: warp+variance+conv1. 16x8 tile, chunked 8ch. blk in [0,800)
__device__ void stageA(int blk, int d,
        const __half* __restrict__ fh, const float* __restrict__ rel,
        const float* __restrict__ depthv, float* __restrict__ c1r,
        const float* __restrict__ W0, const float* __restrict__ Ws1,
        float* buf) {
    const float* s1 = c1r + (size_t)((d+4)%5)*C1SZ;
    float* c1out = c1r + (size_t)(d%5)*C1SZ;
    int bx = blk % 20, by = blk / 20;
    int ox0 = bx*16, oy0 = by*8;
    int tid = threadIdx.x;

    // precompute bilinear taps for this thread's <=2 halo pixels
    int ppix[2]; bool inimg[2];
    int pls[2][8]; float wts[2][8];
#pragma unroll
    for (int j = 0; j < 2; j++) {
        int hp = tid + j*128;
        inimg[j] = false; ppix[j] = 0;
#pragma unroll
        for (int t = 0; t < 8; t++) { pls[j][t] = 0; wts[j][t] = 0.0f; }
        if (hp < ANH) {
            int hy = hp / AHW, hx = hp - hy*AHW;
            int gy = oy0 + hy - 1, gx = ox0 + hx - 1;
            if (gy >= 0 && gy < HH && gx >= 0 && gx < WW) {
                inimg[j] = true;
                int p = gy*WW + gx; ppix[j] = p;
                float depth = depthv[(size_t)d*NP + p];
                float fx = (float)gx, fy = (float)gy;
#pragma unroll
                for (int v = 0; v < 2; v++) {
                    const float* r = rel + v*12;
                    float X = (r[0]*fx + r[1]*fy + r[2]) * depth + r[9];
                    float Y = (r[3]*fx + r[4]*fy + r[5]) * depth + r[10];
                    float Z = (r[6]*fx + r[7]*fy + r[8]) * depth + r[11];
                    float iz = 1.0f / Z;
                    float px = X*iz, py = Y*iz;
                    float x0f = floorf(px), y0f = floorf(py);
                    float wx = px - x0f, wy = py - y0f;
                    int x0 = (int)x0f, y0 = (int)y0f;
#pragma unroll
                    for (int t = 0; t < 4; t++) {
                        int xi = x0 + (t&1), yi = y0 + (t>>1);
                        float wgt = ((t&1)?wx:1.0f-wx) * ((t>>1)?wy:1.0f-wy);
                        bool val = (xi>=0)&&(xi<WW)&&(yi>=0)&&(yi<HH);
                        int xc = min(max(xi,0),WW-1), yc = min(max(yi,0),HH-1);
                        pls[j][v*4+t] = yc*WW + xc;
                        wts[j][v*4+t] = val ? wgt : 0.0f;
                    }
                }
            }
        }
    }

    int opx = tid & 15, opy = tid >> 4;   // 16x8 outputs
    float acc[8];
#pragma unroll
    for (int o = 0; o < 8; o++) acc[o] = 0.0f;
    const float inv3 = 1.0f/3.0f;

    for (int chunk = 0; chunk < 4; chunk++) {
        int c0 = chunk*8;
#pragma unroll
        for (int j = 0; j < 2; j++) {
            int hp = tid + j*128;
            if (hp < ANH) {
                float out8[8];
                if (!inimg[j]) {
#pragma unroll
                    for (int c = 0; c < 8; c++) out8[c] = 0.0f;
                } else {
                    float ref8[8]; load8h(fh + ((size_t)ppix[j]*32 + c0), ref8);
                    float t1[8], t2[8];
#pragma unroll
                    for (int c = 0; c < 8; c++) { t1[c] = 0.0f; t2[c] = 0.0f; }
#pragma unroll
                    for (int t = 0; t < 4; t++) {
                        float tap[8]; load8h(fh + ((size_t)(NP + pls[j][t])*32 + c0), tap);
                        float w = wts[j][t];
#pragma unroll
                        for (int c = 0; c < 8; c++) t1[c] += tap[c]*w;
                    }
#pragma unroll
                    for (int t = 0; t < 4; t++) {
                        float tap[8]; load8h(fh + ((size_t)(2*NP + pls[j][4+t])*32 + c0), tap);
                        float w = wts[j][4+t];
#pragma unroll
                        for (int c = 0; c < 8; c++) t2[c] += tap[c]*w;
                    }
#pragma unroll
                    for (int c = 0; c < 8; c++) {
                        float sum = ref8[c] + t1[c] + t2[c];
                        float sq  = ref8[c]*ref8[c] + t1[c]*t1[c] + t2[c]*t2[c];
                        float m = sum*inv3;
                        out8[c] = sq*inv3 - m*m;
                    }
                }
#pragma unroll
                for (int c = 0; c < 8; c++) buf[c*ABUF_STRIDE + hp] = out8[c];
            }
        }
        __syncthreads();
        for (int ci = 0; ci < 8; ci++) {
            float t[9];
#pragma unroll
            for (int ky = 0; ky < 3; ky++)
#pragma unroll
                for (int kx = 0; kx < 3; kx++)
                    t[ky*3+kx] = buf[ci*ABUF_STRIDE + (opy+ky)*AHW + opx + kx];
#pragma unroll
            for (int o = 0; o < 8; o++) {
                const float* w = W0 + (o*32 + c0 + ci)*9;
                float a = acc[o];
#pragma unroll
                for (int k = 0; k < 9; k++) a += t[k]*w[k];
                acc[o] = a;
            }
        }
        __syncthreads();
    }

    // s1 skip chunk (NHWC ring)
#pragma unroll
    for (int j = 0; j < 2; j++) {
        int hp = tid + j*128;
        if (hp < ANH) {
            float v8[8];
            if (inimg[j]) load8f(s1 + (size_t)ppix[j]*8, v8);
            else { for (int c = 0; c < 8; c++) v8[c] = 0.0f; }
#pragma unroll
            for (int c = 0; c < 8; c++) buf[c*ABUF_STRIDE + hp] = v8[c];
        }
    }
    __syncthreads();
    for (int ci = 0; ci < 8; ci++) {
        float t[9];
#pragma unroll
        for (int ky = 0; ky < 3; ky++)
#pragma unroll
            for (int kx = 0; kx < 3; kx++)
                t[ky*3+kx] = buf[ci*ABUF_STRIDE + (opy+ky)*AHW + opx + kx];
#pragma unroll
        for (int o = 0; o < 8; o++) {
            const float* w = Ws1 + (o*8 + ci)*9;
            float a = acc[o];
#pragma unroll
            for (int k = 0; k < 9; k++) a += t[k]*w[k];
            acc[o] = a;
        }
    }
    int outp = (oy0 + opy)*WW + ox0 + opx;
    float4 r0, r1;
    r0.x = fmaxf(acc[0],0.0f); r0.y = fmaxf(acc[1],0.0f); r0.z = fmaxf(acc[2],0.0f); r0.w = fmaxf(acc[3],0.0f);
    r1.x = fmaxf(acc[4],0.0f); r1.y = fmaxf(acc[5],0.0f); r1.z = fmaxf(acc[6],0.0f); r1.w = fmaxf(acc[7],0.0f);
    float4* dst = (float4*)(c1out + (size_t)outp*8);
    dst[0] = r0; dst[1] = r1;
}

// B: conv2. blk in [0,800): px_chunk = blk%200, og = blk/200 (4 groups of 4)
__device__ void stageB(int blk, int d,
        const float* __restrict__ c1r, float* __restrict__ c2r,
        const float* __restrict__ W1, const float* __restrict__ Ws2) {
    const float* c1 = c1r + (size_t)(d%5)*C1SZ;
    const float* s2 = c2r + (size_t)((d+3)%4)*C2SZ;
    float* c2 = c2r + (size_t)(d%4)*C2SZ;
    int p = (blk % 200)*128 + threadIdx.x;   // 200*128 == N2
    int og = blk / 200;
    int y = p / W2, x = p - y*W2;
    float acc[4] = {0.0f,0.0f,0.0f,0.0f};
#pragma unroll
    for (int ky = 0; ky < 3; ky++) {
#pragma unroll
        for (int kx = 0; kx < 3; kx++) {
            int k = ky*3+kx;
            int yy = 2*y+ky, xx = 2*x+kx;
            if (yy < HH && xx < WW) {
                float v8[8]; load8f(c1 + (size_t)(yy*WW+xx)*8, v8);
#pragma unroll
                for (int o = 0; o < 4; o++) {
                    const float* w = W1 + ((og*4+o)*8)*9 + k;
                    float a = acc[o];
#pragma unroll
                    for (int ci = 0; ci < 8; ci++) a += v8[ci]*w[ci*9];
                    acc[o] = a;
                }
            }
        }
    }
#pragma unroll
    for (int ky = 0; ky < 3; ky++) {
#pragma unroll
        for (int kx = 0; kx < 3; kx++) {
            int k = ky*3+kx;
            int yy = y+ky-1, xx = x+kx-1;
            if (yy >= 0 && yy < H2 && xx >= 0 && xx < W2) {
                float v16[16]; load16f(s2 + (size_t)(yy*W2+xx)*16, v16);
#pragma unroll
                for (int o = 0; o < 4; o++) {
                    const float* w = Ws2 + ((og*4+o)*16)*9 + k;
                    float a = acc[o];
#pragma unroll
                    for (int ci = 0; ci < 16; ci++) a += v16[ci]*w[ci*9];
                    acc[o] = a;
                }
            }
        }
    }
    float4 r;
    r.x = fmaxf(acc[0],0.0f); r.y = fmaxf(acc[1],0.0f); r.z = fmaxf(acc[2],0.0f); r.w = fmaxf(acc[3],0.0f);
    *((float4*)(c2 + (size_t)p*16 + og*4)) = r;
}

// C: conv3. blk in [0,400): px_chunk = blk%50, og = blk/50 (8 groups of 4)
__device__ void stageC(int blk, int d,
        const float* __restrict__ c2r, float* __restrict__ c3r,
        const float* __restrict__ W2w, const float* __restrict__ Ws3) {
    const float* c2 = c2r + (size_t)(d%4)*C2SZ;
    const float* s3 = c3r + (size_t)((d+2)%3)*C3SZ;
    float* c3 = c3r + (size_t)(d%3)*C3SZ;
    int p = (blk % 50)*128 + threadIdx.x;    // 50*128 == N4
    int og = blk / 50;
    int y = p / W4, x = p - y*W4;
    float acc[4] = {0.0f,0.0f,0.0f,0.0f};
#pragma unroll
    for (int ky = 0; ky < 3; ky++) {
#pragma unroll
        for (int kx = 0; kx < 3; kx++) {
            int k = ky*3+kx;
            int yy = 2*y+ky, xx = 2*x+kx;
            if (yy < H2 && xx < W2) {
                float v16[16]; load16f(c2 + (size_t)(yy*W2+xx)*16, v16);
#pragma unroll
                for (int o = 0; o < 4; o++) {
                    const float* w = W2w + ((og*4+o)*16)*9 + k;
                    float a = acc[o];
#pragma unroll
                    for (int ci = 0; ci < 16; ci++) a += v16[ci]*w[ci*9];
                    acc[o] = a;
                }
            }
        }
    }
#pragma unroll
    for (int ky = 0; ky < 3; ky++) {
#pragma unroll
        for (int kx = 0; kx < 3; kx++) {
            int k = ky*3+kx;
            int yy = y+ky-1, xx = x+kx-1;
            if (yy >= 0 && yy < H4 && xx >= 0 && xx < W4) {
                const float4* b = (const float4*)(s3 + (size_t)(yy*W4+xx)*32);
#pragma unroll
                for (int q = 0; q < 8; q++) {
                    float4 v = b[q];
#pragma unroll
                    for (int o = 0; o < 4; o++) {
                        const float* w = Ws3 + ((og*4+o)*32 + q*4)*9 + k;
                        acc[o] += v.x*w[0] + v.y*w[9] + v.z*w[18] + v.w*w[27];
                    }
                }
            }
        }
    }
    float4 r;
    r.x = fmaxf(acc[0],0.0f); r.y = fmaxf(acc[1],0.0f); r.z = fmaxf(acc[2],0.0f); r.w = fmaxf(acc[3],0.0f);
    *((float4*)(c3 + (size_t)p*32 + og*4)) = r;
}

// D: conv4. blk in [0,208): px_chunk = blk%13, og = blk/13 (16 groups of 4)
__device__ void stageD(int blk, int d,
        const float* __restrict__ c3r, float* __restrict__ c4r,
        const float* __restrict__ W3w, const float* __restrict__ Ws4) {
    const float* c3 = c3r + (size_t)(d%3)*C3SZ;
    const float* s4 = c4r + (size_t)((d+1)%2)*C4SZ;
    float* c4 = c4r + (size_t)(d%2)*C4SZ;
    int p = (blk % 13)*128 + threadIdx.x;
    if (p >= N8) return;
    int og = blk / 13;
    int y = p / W8, x = p - y*W8;
    float acc[4] = {0.0f,0.0f,0.0f,0.0f};
#pragma unroll
    for (int ky = 0; ky < 3; ky++) {
#pragma unroll
        for (int kx = 0; kx < 3; kx++) {
            int k = ky*3+kx;
            int yy = 2*y+ky, xx = 2*x+kx;
            if (yy < H4 && xx < W4) {
                const float4* b = (const float4*)(c3 + (size_t)(yy*W4+xx)*32);
#pragma unroll
                for (int q = 0; q < 8; q++) {
                    float4 v = b[q];
#pragma unroll
                    for (int o = 0; o < 4; o++) {
                        const float* w = W3w + ((og*4+o)*32 + q*4)*9 + k;
                        acc[o] += v.x*w[0] + v.y*w[9] + v.z*w[18] + v.w*w[27];
                    }
                }
            }
        }
    }
#pragma unroll
    for (int ky = 0; ky < 3; ky++) {
#pragma unroll
        for (int kx = 0; kx < 3; kx++) {
            int k = ky*3+kx;
            int yy = y+ky-1, xx = x+kx-1;
            if (yy >= 0 && yy < H8 && xx >= 0 && xx < W8) {
                const float4* b = (const float4*)(s4 + (size_t)(yy*W8+xx)*64);
#pragma unroll
                for (int q = 0; q < 16; q++) {
                    float4 v = b[q];
#pragma unroll
                    for (int o = 0; o < 4; o++) {
                        const float* w = Ws4 + ((og*4+o)*64 + q*4)*9 + k;
                        acc[o] += v.x*w[0] + v.y*w[9] + v.z*w[18] + v.w*w[27];
                    }
                }
            }
        }
    }
    float4 r;
    r.x = fmaxf(acc[0],0.0f); r.y = fmaxf(acc[1],0.0f); r.z = fmaxf(acc[2],0.0f); r.w = fmaxf(acc[3],0.0f);
    *((float4*)(c4 + (size_t)p*64 + og*4)) = r;
}

// U: up4+up3+up2+cost+accumulate. 16x8 tile. blk in [0,800)
__device__ void stageU(int blk, int d,
        const float* __restrict__ c1r, const float* __restrict__ c2r,
        const float* __restrict__ c3r, const float* __restrict__ c4r,
        const float* __restrict__ U4, const float* __restrict__ U3w,
        const float* __restrict__ U2w, const float* __restrict__ Wout,
        const float* __restrict__ depthv,
        float* __restrict__ esum, float* __restrict__ dimg,
        float* __restrict__ maxp, float* smem) {
    const float* c1 = c1r + (size_t)(d%5)*C1SZ;
    const float* c2 = c2r + (size_t)(d%4)*C2SZ;
    const float* c3 = c3r + (size_t)(d%3)*C3SZ;
    const float* c4 = c4r + (size_t)(d%2)*C4SZ;
    const float* dsl = depthv + (size_t)d*NP;
    float* u3s = smem;
    float* u2s = smem + U3_PX*U3_STRIDE;
    float* u1s = u2s + U2_PX*U2_STRIDE;
    int bx = blk % 20, by = blk / 20;
    int x0 = bx*16, y0 = by*8;
    int qx0 = (x0>>2) - 1, qy0 = (y0>>2) - 1;
    int hx0 = (x0>>1) - 1, hy0 = (y0>>1) - 1;
    int tid = threadIdx.x;

    // u3 = c3 + up2(conv1x1(c4,U4)) over 6x4 region
    for (int i = tid; i < U3_PX*32; i += 128) {
        int ch = i & 31, pp = i >> 5;
        int y4 = qy0 + pp/6, x4 = qx0 + pp%6;
        int y4c = min(max(y4,0),H4-1), x4c = min(max(x4,0),W4-1);
        int pl = (y4c>>1)*W8 + (x4c>>1);
        const float* w = U4 + ch*64;
        const float* b = c4 + (size_t)pl*64;
        float s = c3[(size_t)(y4c*W4+x4c)*32 + ch];
#pragma unroll 8
        for (int ci = 0; ci < 64; ci++) s += b[ci]*w[ci];
        u3s[pp*U3_STRIDE + ch] = s;
    }
    __syncthreads();
    // u2 = c2 + up2(conv1x1(u3,U3)) over 10x6 region
    for (int i = tid; i < U2_PX*16; i += 128) {
        int ch = i & 15, pp = i >> 4;
        int y2 = hy0 + pp/10, x2 = hx0 + pp%10;
        int y2c = min(max(y2,0),H2-1), x2c = min(max(x2,0),W2-1);
        int ly = (y2c>>1)-qy0, lx = (x2c>>1)-qx0;
        const float* w = U3w + ch*32;
        const float* b = u3s + (ly*6+lx)*U3_STRIDE;
        float s = c2[(size_t)(y2c*W2+x2c)*16 + ch];
#pragma unroll 8
        for (int ci = 0; ci < 32; ci++) s += b[ci]*w[ci];
        u2s[pp*U2_STRIDE + ch] = s;
    }
    __syncthreads();
    // u1 = c1 + up2(conv1x1(u2,U2)) over 18x10 halo (zero outside image)
#pragma unroll
    for (int j = 0; j < 2; j++) {
        int pp = tid + j*128;
        if (pp < U1_PX) {
            int gy = y0 + pp/AHW - 1, gx = x0 + pp%AHW - 1;
            if (gy >= 0 && gy < HH && gx >= 0 && gx < WW) {
                int ly = (gy>>1)-hy0, lx = (gx>>1)-hx0;
                const float* b = u2s + (ly*10+lx)*U2_STRIDE;
                float v8[8]; load8f(c1 + (size_t)(gy*WW+gx)*8, v8);
#pragma unroll
                for (int ch = 0; ch < 8; ch++) {
                    const float* w = U2w + ch*16;
                    float s = v8[ch];
#pragma unroll
                    for (int ci = 0; ci < 16; ci++) s += b[ci]*w[ci];
                    u1s[pp*U1_STRIDE + ch] = s;
                }
            } else {
#pragma unroll
                for (int ch = 0; ch < 8; ch++) u1s[pp*U1_STRIDE + ch] = 0.0f;
            }
        }
    }
    __syncthreads();
    int opx = tid & 15, opy = tid >> 4;
    float cost = 0.0f;
#pragma unroll
    for (int ky = 0; ky < 3; ky++)
#pragma unroll
        for (int kx = 0; kx < 3; kx++) {
            const float* b = u1s + ((opy+ky)*AHW + opx+kx)*U1_STRIDE;
#pragma unroll
            for (int ch = 0; ch < 8; ch++) cost += b[ch]*Wout[ch*9 + ky*3+kx];
        }
    int p = (y0+opy)*WW + x0 + opx;
    float prob = expf(cost);
    esum[p] += prob;
    dimg[p] += dsl[p]*prob;
    maxp[p] = fmaxf(maxp[p], prob);
}

// ================= uber kernel: one diagonal of the pipeline =================
__global__ __launch_bounds__(128, 6) void k_uber(
        int t,
        const __half* __restrict__ fh, const float* __restrict__ rel,
        const float* __restrict__ depthv,
        const float* __restrict__ W0, const float* __restrict__ Ws1,
        const float* __restrict__ W1, const float* __restrict__ Ws2,
        const float* __restrict__ W2w, const float* __restrict__ Ws3,
        const float* __restrict__ W3w, const float* __restrict__ Ws4,
        const float* __restrict__ U4, const float* __restrict__ U3,
        const float* __restrict__ U2, const float* __restrict__ Wout,
        float* __restrict__ c1r, float* __restrict__ c2r,
        float* __restrict__ c3r, float* __restrict__ c4r,
        float* __restrict__ esum, float* __restrict__ dimg,
        float* __restrict__ maxp) {
    __shared__ float smem[SMEM_FLOATS];   // 13728 B
    int b = blockIdx.x;
    if (b < A_END) {
        int d = t;
        if (d < DD) stageA(b, d, fh, rel, depthv, c1r, W0, Ws1, smem);
    } else if (b < B_END) {
        int d = t - 1;
        if (d >= 0 && d < DD) stageB(b - A_END, d, c1r, c2r, W1, Ws2);
    } else if (b < C_END) {
        int d = t - 2;
        if (d >= 0 && d < DD) stageC(b - B_END, d, c2r, c3r, W2w, Ws3);
    } else if (b < D_END) {
        int d = t - 3;
        if (d >= 0 && d < DD) stageD(b - C_END, d, c3r, c4r, W3w, Ws4);
    } else {
        int d = t - 4;
        if (d >= 0 && d < DD)
            stageU(b - D_END, d, c1r, c2r, c3r, c4r, U4, U3, U2, Wout, depthv,
                   esum, dimg, maxp, smem);
    }
}

// ---------------- final normalize ----------------
__global__ __launch_bounds__(256) void k_final(
        const float* __restrict__ exp_sum, const float* __restrict__ depth_img,
        const float* __restrict__ max_prob, float* __restrict__ out) {
    int p = blockIdx.x*256 + threadIdx.x;
    if (p >= NP) return;
    float es = exp_sum[p] + 1e-10f;
    out[p] = depth_img[p] / es;
    out[NP + p] = max_prob[p] / es;
}

extern "C" void kernel_launch(void* const* d_in, const int* in_sizes, int n_in,
                              void* d_out, int out_size, void* d_ws, size_t ws_size,
                              hipStream_t stream) {
    const float* feats = (const float*)d_in[0];
    const float* proj  = (const float*)d_in[1];
    const float* depthv= (const float*)d_in[2];
    const float* W0  = (const float*)d_in[3];
    const float* Ws1 = (const float*)d_in[4];
    const float* W1  = (const float*)d_in[5];
    const float* Ws2 = (const float*)d_in[6];
    const float* W2w = (const float*)d_in[7];
    const float* Ws3 = (const float*)d_in[8];
    const float* W3w = (const float*)d_in[9];
    const float* Ws4 = (const float*)d_in[10];
    const float* U4  = (const float*)d_in[11];
    const float* U3  = (const float*)d_in[12];
    const float* U2  = (const float*)d_in[13];
    const float* Wout= (const float*)d_in[14];

    float* ws = (float*)d_ws;
    float* rel  = ws + OFF_REL;
    __half* fh  = (__half*)(ws + OFF_FH);
    float* c1r  = ws + OFF_C1R;
    float* c2r  = ws + OFF_C2R;
    float* c3r  = ws + OFF_C3R;
    float* c4r  = ws + OFF_C4R;
    float* esum = ws + OFF_ESUM;
    float* dimg = ws + OFF_DIMG;
    float* maxp = ws + OFF_MAXP;

    // zero rings + accumulators (ring slots double as the zero "previous
    // skip" inputs for d=0). fh/rel are fully written each call.
    hipMemsetAsync(c1r, 0, (size_t)(OFF_END - OFF_C1R) * sizeof(float), stream);
    k_prep<<<1, 1, 0, stream>>>(proj, rel);
    k_tofp16<<<dim3((3*NP + 255)/256), 256, 0, stream>>>(feats, fh);

    for (int t = 0; t < DD + 4; t++) {
        k_uber<<<dim3(TOT_BLK), 128, 0, stream>>>(t, fh, rel, depthv,
            W0, Ws1, W1, Ws2, W2w, Ws3, W3w, Ws4, U4, U3, U2, Wout,
            c1r, c2r, c3r, c4r, esum, dimg, maxp);
    }
    k_final<<<dim3(400), 256, 0, stream>>>(esum, dimg, maxp, (float*)d_out);
}

// Round 6
// 3038.465 us; speedup vs baseline: 1.2199x; 1.2199x over previous
//
#include <hip/hip_runtime.h>
#include <hip/hip_bf16.h>
#include <hip/hip_fp16.h>
#include <math.h>

// Problem constants
#define HH 320
#define WW 320
#define NP (HH*WW)        // 102400
#define CC 32
#define DD 32
#define H2 160
#define W2 160
#define N2 (H2*W2)
#define H4 80
#define W4 80
#define N4 (H4*W4)
#define H8 40
#define W8 40
#define N8 (H8*W8)

// stage A / U tile: 16 wide x 8 high
#define AHW 18
#define AHH 10
#define ANH (AHW*AHH)      // 180
#define ABUF_STRIDE 184    // per-channel LDS row stride (breaks pow2)

// stage U LDS layouts (NCHW-style [ch][px], padded)
#define U3_NPX 24          // 6x4 quarter-res region
#define U3_ST  25
#define U2_NPX 60          // 10x6 half-res region
#define U2_ST  61
#define U1_NPX 180         // 18x10 full-res halo
#define U1_ST  181

#define SMEM_FLOATS (32*U3_ST + 16*U2_ST + 8*U1_ST)  // 800+976+1448 = 3224 fl = 12.9 KB
// stage A uses 8*ABUF_STRIDE = 1472 floats (prefix)

// ring strides (floats); rings are NCHW fp32: [ch][pix]
#define C1SZ (8*NP)
#define C2SZ (16*N2)
#define C3SZ (32*N4)
#define C4SZ (64*N8)

// workspace layout (float offsets)
#define OFF_REL  0
#define FH_FLOATS (3*CC*NP/2)              // fp16 NCHW feats (same layout as input)
#define OFF_FH   64
#define OFF_C1R  (OFF_FH + FH_FLOATS)      // ring of 5
#define OFF_C2R  (OFF_C1R + 5*C1SZ)        // ring of 4
#define OFF_C3R  (OFF_C2R + 4*C2SZ)        // ring of 3
#define OFF_C4R  (OFF_C3R + 3*C3SZ)        // ring of 2
#define OFF_ESUM (OFF_C4R + 2*C4SZ)
#define OFF_DIMG (OFF_ESUM + NP)
#define OFF_MAXP (OFF_DIMG + NP)
#define OFF_END  (OFF_MAXP + NP)

// uber grid: block ranges (all 128-thread)
#define A_END 800
#define B_END 1600
#define C_END 2000
#define D_END 2208
#define TOT_BLK 3008

// ---------------- prep: rel = proj[v] @ inv(proj[0]), v=1,2 ----------------
__global__ void k_prep(const float* __restrict__ proj, float* __restrict__ rel) {
    if (threadIdx.x != 0 || blockIdx.x != 0) return;
    double a[4][8];
    for (int i = 0; i < 4; i++)
        for (int j = 0; j < 4; j++) {
            a[i][j] = (double)proj[i*4 + j];
            a[i][j+4] = (i == j) ? 1.0 : 0.0;
        }
    for (int c = 0; c < 4; c++) {
        int pv = c; double best = fabs(a[c][c]);
        for (int r = c+1; r < 4; r++) {
            double v = fabs(a[r][c]);
            if (v > best) { best = v; pv = r; }
        }
        if (pv != c)
            for (int j = 0; j < 8; j++) { double t = a[c][j]; a[c][j] = a[pv][j]; a[pv][j] = t; }
        double inv = 1.0 / a[c][c];
        for (int j = 0; j < 8; j++) a[c][j] *= inv;
        for (int r = 0; r < 4; r++) if (r != c) {
            double f = a[r][c];
            for (int j = 0; j < 8; j++) a[r][j] -= f * a[c][j];
        }
    }
    for (int v = 1; v < 3; v++) {
        const float* P = proj + v*16;
        double rm[4][4];
        for (int i = 0; i < 4; i++)
            for (int j = 0; j < 4; j++) {
                double s = 0.0;
                for (int k = 0; k < 4; k++) s += (double)P[i*4 + k] * a[k][j+4];
                rm[i][j] = s;
            }
        float* o = rel + (v-1)*12;
        o[0]=(float)rm[0][0]; o[1]=(float)rm[0][1]; o[2]=(float)rm[0][2];
        o[3]=(float)rm[1][0]; o[4]=(float)rm[1][1]; o[5]=(float)rm[1][2];
        o[6]=(float)rm[2][0]; o[7]=(float)rm[2][1]; o[8]=(float)rm[2][2];
        o[9]=(float)rm[0][3]; o[10]=(float)rm[1][3]; o[11]=(float)rm[2][3];
    }
}

// ---------------- one-time: feats fp32 -> fp16 (same NCHW layout) ----------------
__global__ __launch_bounds__(256) void k_tofp16(const float* __restrict__ feats,
                                                __half* __restrict__ fh) {
    int i = blockIdx.x*256 + threadIdx.x;   // each handles 8 elements
    int base = i*8;
    if (base >= 3*CC*NP) return;
    float4 a = *(const float4*)(feats + base);
    float4 b = *(const float4*)(feats + base + 4);
    __half h[8];
    h[0]=__float2half(a.x); h[1]=__float2half(a.y); h[2]=__float2half(a.z); h[3]=__float2half(a.w);
    h[4]=__float2half(b.x); h[5]=__float2half(b.y); h[6]=__float2half(b.z); h[7]=__float2half(b.w);
    *(float4*)(fh + base) = *(float4*)h;
}

// ================= stage device functions (128 threads each) =================

// A: warp+variance+conv1. 16x8 tile, chunked 8ch. blk in [0,800)
__device__ void stageA(int blk, int d,
        const __half* __restrict__ fh, const float* __restrict__ rel,
        const float* __restrict__ depthv, float* __restrict__ c1r,
        const float* __restrict__ W0, const float* __restrict__ Ws1,
        float* buf) {
    const float* s1 = c1r + (size_t)((d+4)%5)*C1SZ;
    float* c1out = c1r + (size_t)(d%5)*C1SZ;
    int bx = blk % 20, by = blk / 20;
    int ox0 = bx*16, oy0 = by*8;
    int tid = threadIdx.x;

    // precompute taps for this thread's <=2 halo pixels:
    // per view: 2 row base indices (plane-relative) + 4 coefficients
    int ppix[2]; bool inimg[2];
    int rb[2][4];     // [j][v*2+r]
    float cf[2][8];   // [j][v*4 + r*2 + {0,1}]
#pragma unroll
    for (int j = 0; j < 2; j++) {
        int hp = tid + j*128;
        inimg[j] = false; ppix[j] = 0;
#pragma unroll
        for (int q = 0; q < 4; q++) rb[j][q] = 0;
#pragma unroll
        for (int q = 0; q < 8; q++) cf[j][q] = 0.0f;
        if (hp < ANH) {
            int hy = hp / AHW, hx = hp - hy*AHW;
            int gy = oy0 + hy - 1, gx = ox0 + hx - 1;
            if (gy >= 0 && gy < HH && gx >= 0 && gx < WW) {
                inimg[j] = true;
                int p = gy*WW + gx; ppix[j] = p;
                float depth = depthv[(size_t)d*NP + p];
                float fx = (float)gx, fy = (float)gy;
#pragma unroll
                for (int v = 0; v < 2; v++) {
                    const float* r = rel + v*12;
                    float X = (r[0]*fx + r[1]*fy + r[2]) * depth + r[9];
                    float Y = (r[3]*fx + r[4]*fy + r[5]) * depth + r[10];
                    float Z = (r[6]*fx + r[7]*fy + r[8]) * depth + r[11];
                    float iz = 1.0f / Z;
                    float px = fminf(fmaxf(X*iz, -2.0f), (float)(WW+1));
                    float py = fminf(fmaxf(Y*iz, -2.0f), (float)(HH+1));
                    float x0f = floorf(px), y0f = floorf(py);
                    float wx = px - x0f, wy = py - y0f;
                    int x0 = (int)x0f, y0 = (int)y0f;
                    int xb = min(max(x0, 0), WW-2);
                    float cA, cB;
                    if (x0 >= 0 && x0 <= WW-2)      { cA = 1.0f-wx; cB = wx; }
                    else if (x0 == -1)              { cA = wx;      cB = 0.0f; }
                    else if (x0 == WW-1)            { cA = 0.0f;    cB = 1.0f-wx; }
                    else                            { cA = 0.0f;    cB = 0.0f; }
#pragma unroll
                    for (int rr = 0; rr < 2; rr++) {
                        int yr = y0 + rr;
                        float wyr = rr ? wy : 1.0f-wy;
                        bool vy = (yr >= 0) && (yr < HH);
                        int yrc = min(max(yr, 0), HH-1);
                        rb[j][v*2+rr] = yrc*WW + xb;
                        cf[j][v*4+rr*2+0] = vy ? wyr*cA : 0.0f;
                        cf[j][v*4+rr*2+1] = vy ? wyr*cB : 0.0f;
                    }
                }
            }
        }
    }

    int opx = tid & 15, opy = tid >> 4;   // 16x8 outputs
    float acc[8];
#pragma unroll
    for (int o = 0; o < 8; o++) acc[o] = 0.0f;
    const float inv3 = 1.0f/3.0f;

    for (int chunk = 0; chunk < 4; chunk++) {
        int c0 = chunk*8;
#pragma unroll
        for (int j = 0; j < 2; j++) {
            int hp = tid + j*128;
            if (hp < ANH) {
                if (!inimg[j]) {
#pragma unroll
                    for (int c = 0; c < 8; c++) buf[c*ABUF_STRIDE + hp] = 0.0f;
                } else {
                    int p = ppix[j];
#pragma unroll
                    for (int c = 0; c < 8; c++) {
                        int cg = c0 + c;
                        float rv = __half2float(fh[(size_t)cg*NP + p]);
                        const __half* p1 = fh + (size_t)(CC + cg)*NP;
                        float t1 = cf[j][0]*__half2float(p1[rb[j][0]])
                                 + cf[j][1]*__half2float(p1[rb[j][0]+1])
                                 + cf[j][2]*__half2float(p1[rb[j][1]])
                                 + cf[j][3]*__half2float(p1[rb[j][1]+1]);
                        const __half* p2 = fh + (size_t)(2*CC + cg)*NP;
                        float t2 = cf[j][4]*__half2float(p2[rb[j][2]])
                                 + cf[j][5]*__half2float(p2[rb[j][2]+1])
                                 + cf[j][6]*__half2float(p2[rb[j][3]])
                                 + cf[j][7]*__half2float(p2[rb[j][3]+1]);
                        float sum = rv + t1 + t2;
                        float sq  = rv*rv + t1*t1 + t2*t2;
                        float m = sum*inv3;
                        buf[c*ABUF_STRIDE + hp] = sq*inv3 - m*m;
                    }
                }
            }
        }
        __syncthreads();
        for (int ci = 0; ci < 8; ci++) {
            float t[9];
#pragma unroll
            for (int ky = 0; ky < 3; ky++)
#pragma unroll
                for (int kx = 0; kx < 3; kx++)
                    t[ky*3+kx] = buf[ci*ABUF_STRIDE + (opy+ky)*AHW + opx + kx];
#pragma unroll
            for (int o = 0; o < 8; o++) {
                const float* w = W0 + (o*32 + c0 + ci)*9;
                float a = acc[o];
#pragma unroll
                for (int k = 0; k < 9; k++) a += t[k]*w[k];
                acc[o] = a;
            }
        }
        __syncthreads();
    }

    // s1 skip chunk (NCHW fp32 ring)
#pragma unroll
    for (int j = 0; j < 2; j++) {
        int hp = tid + j*128;
        if (hp < ANH) {
#pragma unroll
            for (int c = 0; c < 8; c++)
                buf[c*ABUF_STRIDE + hp] = inimg[j] ? s1[(size_t)c*NP + ppix[j]] : 0.0f;
        }
    }
    __syncthreads();
    for (int ci = 0; ci < 8; ci++) {
        float t[9];
#pragma unroll
        for (int ky = 0; ky < 3; ky++)
#pragma unroll
            for (int kx = 0; kx < 3; kx++)
                t[ky*3+kx] = buf[ci*ABUF_STRIDE + (opy+ky)*AHW + opx + kx];
#pragma unroll
        for (int o = 0; o < 8; o++) {
            const float* w = Ws1 + (o*8 + ci)*9;
            float a = acc[o];
#pragma unroll
            for (int k = 0; k < 9; k++) a += t[k]*w[k];
            acc[o] = a;
        }
    }
    int outp = (oy0 + opy)*WW + ox0 + opx;
#pragma unroll
    for (int o = 0; o < 8; o++) c1out[(size_t)o*NP + outp] = fmaxf(acc[o], 0.0f);
}

// B: conv2. blk in [0,800): px_chunk = blk%200, og = blk/200 (4 groups of 4)
__device__ void stageB(int blk, int d,
        const float* __restrict__ c1r, float* __restrict__ c2r,
        const float* __restrict__ W1, const float* __restrict__ Ws2) {
    const float* c1 = c1r + (size_t)(d%5)*C1SZ;
    const float* s2 = c2r + (size_t)((d+3)%4)*C2SZ;
    float* c2 = c2r + (size_t)(d%4)*C2SZ;
    int p = (blk % 200)*128 + threadIdx.x;   // 200*128 == N2
    int og = blk / 200;
    int y = p / W2, x = p - y*W2;
    int offsA[9]; float mskA[9];
#pragma unroll
    for (int k = 0; k < 9; k++) {
        int yy = 2*y + k/3, xx = 2*x + k%3;
        bool v = (yy < HH) && (xx < WW);
        offsA[k] = v ? yy*WW + xx : 0;
        mskA[k] = v ? 1.0f : 0.0f;
    }
    int offsB[9]; float mskB[9];
#pragma unroll
    for (int k = 0; k < 9; k++) {
        int yy = y + k/3 - 1, xx = x + k%3 - 1;
        bool v = (yy >= 0) && (yy < H2) && (xx >= 0) && (xx < W2);
        offsB[k] = v ? yy*W2 + xx : 0;
        mskB[k] = v ? 1.0f : 0.0f;
    }
    float acc[4] = {0.0f,0.0f,0.0f,0.0f};
    for (int ci = 0; ci < 8; ci++) {
        const float* b = c1 + (size_t)ci*NP;
        float t[9];
#pragma unroll
        for (int k = 0; k < 9; k++) t[k] = b[offsA[k]] * mskA[k];
#pragma unroll
        for (int o = 0; o < 4; o++) {
            const float* w = W1 + ((og*4 + o)*8 + ci)*9;
            float a = acc[o];
#pragma unroll
            for (int k = 0; k < 9; k++) a += t[k]*w[k];
            acc[o] = a;
        }
    }
    for (int ci = 0; ci < 16; ci++) {
        const float* b = s2 + (size_t)ci*N2;
        float t[9];
#pragma unroll
        for (int k = 0; k < 9; k++) t[k] = b[offsB[k]] * mskB[k];
#pragma unroll
        for (int o = 0; o < 4; o++) {
            const float* w = Ws2 + ((og*4 + o)*16 + ci)*9;
            float a = acc[o];
#pragma unroll
            for (int k = 0; k < 9; k++) a += t[k]*w[k];
            acc[o] = a;
        }
    }
#pragma unroll
    for (int o = 0; o < 4; o++) c2[(size_t)(og*4 + o)*N2 + p] = fmaxf(acc[o], 0.0f);
}

// C: conv3. blk in [0,400): px_chunk = blk%50, og = blk/50 (8 groups of 4)
__device__ void stageC(int blk, int d,
        const float* __restrict__ c2r, float* __restrict__ c3r,
        const float* __restrict__ W2w, const float* __restrict__ Ws3) {
    const float* c2 = c2r + (size_t)(d%4)*C2SZ;
    const float* s3 = c3r + (size_t)((d+2)%3)*C3SZ;
    float* c3 = c3r + (size_t)(d%3)*C3SZ;
    int p = (blk % 50)*128 + threadIdx.x;    // 50*128 == N4
    int og = blk / 50;
    int y = p / W4, x = p - y*W4;
    int offsA[9]; float mskA[9];
#pragma unroll
    for (int k = 0; k < 9; k++) {
        int yy = 2*y + k/3, xx = 2*x + k%3;
        bool v = (yy < H2) && (xx < W2);
        offsA[k] = v ? yy*W2 + xx : 0;
        mskA[k] = v ? 1.0f : 0.0f;
    }
    int offsB[9]; float mskB[9];
#pragma unroll
    for (int k = 0; k < 9; k++) {
        int yy = y + k/3 - 1, xx = x + k%3 - 1;
        bool v = (yy >= 0) && (yy < H4) && (xx >= 0) && (xx < W4);
        offsB[k] = v ? yy*W4 + xx : 0;
        mskB[k] = v ? 1.0f : 0.0f;
    }
    float acc[4] = {0.0f,0.0f,0.0f,0.0f};
    for (int ci = 0; ci < 16; ci++) {
        const float* b = c2 + (size_t)ci*N2;
        float t[9];
#pragma unroll
        for (int k = 0; k < 9; k++) t[k] = b[offsA[k]] * mskA[k];
#pragma unroll
        for (int o = 0; o < 4; o++) {
            const float* w = W2w + ((og*4 + o)*16 + ci)*9;
            float a = acc[o];
#pragma unroll
            for (int k = 0; k < 9; k++) a += t[k]*w[k];
            acc[o] = a;
        }
    }
    for (int ci = 0; ci < 32; ci++) {
        const float* b = s3 + (size_t)ci*N4;
        float t[9];
#pragma unroll
        for (int k = 0; k < 9; k++) t[k] = b[offsB[k]] * mskB[k];
#pragma unroll
        for (int o = 0; o < 4; o++) {
            const float* w = Ws3 + ((og*4 + o)*32 + ci)*9;
            float a = acc[o];
#pragma unroll
            for (int k = 0; k < 9; k++) a += t[k]*w[k];
            acc[o] = a;
        }
    }
#pragma unroll
    for (int o = 0; o < 4; o++) c3[(size_t)(og*4 + o)*N4 + p] = fmaxf(acc[o], 0.0f);
}

// D: conv4. blk in [0,208): px_chunk = blk%13, og = blk/13 (16 groups of 4)
__device__ void stageD(int blk, int d,
        const float* __restrict__ c3r, float* __restrict__ c4r,
        const float* __restrict__ W3w, const float* __restrict__ Ws4) {
    const float* c3 = c3r + (size_t)(d%3)*C3SZ;
    const float* s4 = c4r + (size_t)((d+1)%2)*C4SZ;
    float* c4 = c4r + (size_t)(d%2)*C4SZ;
    int p = (blk % 13)*128 + threadIdx.x;
    if (p >= N8) return;
    int og = blk / 13;
    int y = p / W8, x = p - y*W8;
    int offsA[9]; float mskA[9];
#pragma unroll
    for (int k = 0; k < 9; k++) {
        int yy = 2*y + k/3, xx = 2*x + k%3;
        bool v = (yy < H4) && (xx < W4);
        offsA[k] = v ? yy*W4 + xx : 0;
        mskA[k] = v ? 1.0f : 0.0f;
    }
    int offsB[9]; float mskB[9];
#pragma unroll
    for (int k = 0; k < 9; k++) {
        int yy = y + k/3 - 1, xx = x + k%3 - 1;
        bool v = (yy >= 0) && (yy < H8) && (xx >= 0) && (xx < W8);
        offsB[k] = v ? yy*W8 + xx : 0;
        mskB[k] = v ? 1.0f : 0.0f;
    }
    float acc[4] = {0.0f,0.0f,0.0f,0.0f};
    for (int ci = 0; ci < 32; ci++) {
        const float* b = c3 + (size_t)ci*N4;
        float t[9];
#pragma unroll
        for (int k = 0; k < 9; k++) t[k] = b[offsA[k]] * mskA[k];
#pragma unroll
        for (int o = 0; o < 4; o++) {
            const float* w = W3w + ((og*4 + o)*32 + ci)*9;
            float a = acc[o];
#pragma unroll
            for (int k = 0; k < 9; k++) a += t[k]*w[k];
            acc[o] = a;
        }
    }
    for (int ci = 0; ci < 64; ci++) {
        const float* b = s4 + (size_t)ci*N8;
        float t[9];
#pragma unroll
        for (int k = 0; k < 9; k++) t[k] = b[offsB[k]] * mskB[k];
#pragma unroll
        for (int o = 0; o < 4; o++) {
            const float* w = Ws4 + ((og*4 + o)*64 + ci)*9;
            float a = acc[o];
#pragma unroll
            for (int k = 0; k < 9; k++) a += t[k]*w[k];
            acc[o] = a;
        }
    }
#pragma unroll
    for (int o = 0; o < 4; o++) c4[(size_t)(og*4 + o)*N8 + p] = fmaxf(acc[o], 0.0f);
}

// U: up4+up3+up2+cost+accumulate. 16x8 tile. blk in [0,800)
__device__ void stageU(int blk, int d,
        const float* __restrict__ c1r, const float* __restrict__ c2r,
        const float* __restrict__ c3r, const float* __restrict__ c4r,
        const float* __restrict__ U4, const float* __restrict__ U3w,
        const float* __restrict__ U2w, const float* __restrict__ Wout,
        const float* __restrict__ depthv,
        float* __restrict__ esum, float* __restrict__ dimg,
        float* __restrict__ maxp, float* smem) {
    const float* c1 = c1r + (size_t)(d%5)*C1SZ;
    const float* c2 = c2r + (size_t)(d%4)*C2SZ;
    const float* c3 = c3r + (size_t)(d%3)*C3SZ;
    const float* c4 = c4r + (size_t)(d%2)*C4SZ;
    const float* dsl = depthv + (size_t)d*NP;
    float* u3s = smem;                    // [32][U3_ST]
    float* u2s = smem + 32*U3_ST;         // [16][U2_ST]
    float* u1s = u2s + 16*U2_ST;          // [8][U1_ST]
    int bx = blk % 20, by = blk / 20;
    int x0 = bx*16, y0 = by*8;
    int qx0 = (x0>>2) - 1, qy0 = (y0>>2) - 1;
    int hx0 = (x0>>1) - 1, hy0 = (y0>>1) - 1;
    int tid = threadIdx.x;

    // u3 = c3 + up2(conv1x1(c4,U4)) over 6x4 region
    for (int i = tid; i < 32*U3_NPX; i += 128) {
        int ch = i / U3_NPX, pp = i - ch*U3_NPX;
        int y4 = qy0 + pp/6, x4 = qx0 + pp%6;
        int y4c = min(max(y4,0),H4-1), x4c = min(max(x4,0),W4-1);
        int pl = (y4c>>1)*W8 + (x4c>>1);
        const float* w = U4 + ch*64;
        float s = c3[(size_t)ch*N4 + y4c*W4 + x4c];
#pragma unroll 8
        for (int ci = 0; ci < 64; ci++) s += c4[(size_t)ci*N8 + pl]*w[ci];
        u3s[ch*U3_ST + pp] = s;
    }
    __syncthreads();
    // u2 = c2 + up2(conv1x1(u3,U3)) over 10x6 region
    for (int i = tid; i < 16*U2_NPX; i += 128) {
        int ch = i / U2_NPX, pp = i - ch*U2_NPX;
        int y2 = hy0 + pp/10, x2 = hx0 + pp%10;
        int y2c = min(max(y2,0),H2-1), x2c = min(max(x2,0),W2-1);
        int ly = (y2c>>1)-qy0, lx = (x2c>>1)-qx0;
        const float* w = U3w + ch*32;
        float s = c2[(size_t)ch*N2 + y2c*W2 + x2c];
#pragma unroll 8
        for (int ci = 0; ci < 32; ci++) s += u3s[ci*U3_ST + ly*6 + lx]*w[ci];
        u2s[ch*U2_ST + pp] = s;
    }
    __syncthreads();
    // u1 = c1 + up2(conv1x1(u2,U2)) over 18x10 halo (zero outside image)
    for (int i = tid; i < 8*U1_NPX; i += 128) {
        int ch = i / U1_NPX, pp = i - ch*U1_NPX;
        int gy = y0 + pp/AHW - 1, gx = x0 + pp%AHW - 1;
        float s = 0.0f;
        if (gy >= 0 && gy < HH && gx >= 0 && gx < WW) {
            int ly = (gy>>1)-hy0, lx = (gx>>1)-hx0;
            const float* w = U2w + ch*16;
            s = c1[(size_t)ch*NP + gy*WW + gx];
#pragma unroll
            for (int ci = 0; ci < 16; ci++) s += u2s[ci*U2_ST + ly*10 + lx]*w[ci];
        }
        u1s[ch*U1_ST + pp] = s;
    }
    __syncthreads();
    int opx = tid & 15, opy = tid >> 4;
    int base = opy*AHW + opx;
    float cost = 0.0f;
#pragma unroll
    for (int ci = 0; ci < 8; ci++) {
        const float* w = Wout + ci*9;
#pragma unroll
        for (int ky = 0; ky < 3; ky++)
#pragma unroll
            for (int kx = 0; kx < 3; kx++)
                cost += u1s[ci*U1_ST + base + ky*AHW + kx]*w[ky*3+kx];
    }
    int p = (y0+opy)*WW + x0 + opx;
    float prob = expf(cost);
    esum[p] += prob;
    dimg[p] += dsl[p]*prob;
    maxp[p] = fmaxf(maxp[p], prob);
}

// ================= uber kernel: one diagonal of the pipeline =================
__global__ __launch_bounds__(128) void k_uber(
        int t,
        const __half* __restrict__ fh, const float* __restrict__ rel,
        const float* __restrict__ depthv,
        const float* __restrict__ W0, const float* __restrict__ Ws1,
        const float* __restrict__ W1, const float* __restrict__ Ws2,
        const float* __restrict__ W2w, const float* __restrict__ Ws3,
        const float* __restrict__ W3w, const float* __restrict__ Ws4,
        const float* __restrict__ U4, const float* __restrict__ U3,
        const float* __restrict__ U2, const float* __restrict__ Wout,
        float* __restrict__ c1r, float* __restrict__ c2r,
        float* __restrict__ c3r, float* __restrict__ c4r,
        float* __restrict__ esum, float* __restrict__ dimg,
        float* __restrict__ maxp) {
    __shared__ float smem[SMEM_FLOATS];   // 12.9 KB
    int b = blockIdx.x;
    if (b < A_END) {
        int d = t;
        if (d < DD) stageA(b, d, fh, rel, depthv, c1r, W0, Ws1, smem);
    } else if (b < B_END) {
        int d = t - 1;
        if (d >= 0 && d < DD) stageB(b - A_END, d, c1r, c2r, W1, Ws2);
    } else if (b < C_END) {
        int d = t - 2;
        if (d >= 0 && d < DD) stageC(b - B_END, d, c2r, c3r, W2w, Ws3);
    } else if (b < D_END) {
        int d = t - 3;
        if (d >= 0 && d < DD) stageD(b - C_END, d, c3r, c4r, W3w, Ws4);
    } else {
        int d = t - 4;
        if (d >= 0 && d < DD)
            stageU(b - D_END, d, c1r, c2r, c3r, c4r, U4, U3, U2, Wout, depthv,
                   esum, dimg, maxp, smem);
    }
}

// ---------------- final normalize ----------------
__global__ __launch_bounds__(256) void k_final(
        const float* __restrict__ exp_sum, const float* __restrict__ depth_img,
        const float* __restrict__ max_prob, float* __restrict__ out) {
    int p = blockIdx.x*256 + threadIdx.x;
    if (p >= NP) return;
    float es = exp_sum[p] + 1e-10f;
    out[p] = depth_img[p] / es;
    out[NP + p] = max_prob[p] / es;
}

extern "C" void kernel_launch(void* const* d_in, const int* in_sizes, int n_in,
                              void* d_out, int out_size, void* d_ws, size_t ws_size,
                              hipStream_t stream) {
    const float* feats = (const float*)d_in[0];
    const float* proj  = (const float*)d_in[1];
    const float* depthv= (const float*)d_in[2];
    const float* W0  = (const float*)d_in[3];
    const float* Ws1 = (const float*)d_in[4];
    const float* W1  = (const float*)d_in[5];
    const float* Ws2 = (const float*)d_in[6];
    const float* W2w = (const float*)d_in[7];
    const float* Ws3 = (const float*)d_in[8];
    const float* W3w = (const float*)d_in[9];
    const float* Ws4 = (const float*)d_in[10];
    const float* U4  = (const float*)d_in[11];
    const float* U3  = (const float*)d_in[12];
    const float* U2  = (const float*)d_in[13];
    const float* Wout= (const float*)d_in[14];

    float* ws = (float*)d_ws;
    float* rel  = ws + OFF_REL;
    __half* fh  = (__half*)(ws + OFF_FH);
    float* c1r  = ws + OFF_C1R;
    float* c2r  = ws + OFF_C2R;
    float* c3r  = ws + OFF_C3R;
    float* c4r  = ws + OFF_C4R;
    float* esum = ws + OFF_ESUM;
    float* dimg = ws + OFF_DIMG;
    float* maxp = ws + OFF_MAXP;

    // zero rings + accumulators (ring slots double as the zero "previous
    // skip" inputs for d=0). fh/rel fully written below before use.
    hipMemsetAsync(c1r, 0, (size_t)(OFF_END - OFF_C1R) * sizeof(float), stream);
    k_prep<<<1, 1, 0, stream>>>(proj, rel);
    k_tofp16<<<dim3(3*CC*NP/8/256), 256, 0, stream>>>(feats, fh);

    for (int t = 0; t < DD + 4; t++) {
        k_uber<<<dim3(TOT_BLK), 128, 0, stream>>>(t, fh, rel, depthv,
            W0, Ws1, W1, Ws2, W2w, Ws3, W3w, Ws4, U4, U3, U2, Wout,
            c1r, c2r, c3r, c4r, esum, dimg, maxp);
    }
    k_final<<<dim3(400), 256, 0, stream>>>(esum, dimg, maxp, (float*)d_out);
}